// Round 16
// baseline (1419.423 us; speedup 1.0000x reference)
//
#include <hip/hip_runtime.h>
#include <math.h>

// Problem constants
constexpr int kT = 2048;   // tokens (B*S)
constexpr int kH = 1024;   // hidden
constexpr int kI = 4096;   // ffn inner
constexpr int kE = 8;      // experts
constexpr int kV = 32000;  // vocab
constexpr int kL = 2;      // layers
constexpr int kR = 4096;   // total routed rows = K*T
constexpr int kRp = 5120;  // padded compact rows (off[e] 128-aligned)
constexpr int kSK = 4;     // fc2 split-K chunks
constexpr int kNB = kR / 128 + kE - 1;  // 39: max active m-blocks across experts

typedef __attribute__((ext_vector_type(4))) float f32x4;
typedef __attribute__((ext_vector_type(8))) short bf16x8;

// f32 pair -> packed bf16x2 (gfx950 v_cvt_pk_bf16_f32; RNE — same as f2bf)
__device__ inline unsigned cvtpk(float lo, float hi) {
  unsigned r;
  asm("v_cvt_pk_bf16_f32 %0, %1, %2" : "=v"(r) : "v"(lo), "v"(hi));
  return r;
}

__device__ inline unsigned short f2bf(float x) {
  union { float f; unsigned u; } c; c.f = x;
  unsigned u = c.u;
  u += 0x7FFFu + ((u >> 16) & 1u);  // RNE
  return (unsigned short)(u >> 16);
}

// bf16x3 exact-truncation decompose of an f32 pair, packed per level.
__device__ inline void dec2(float x, float y,
                            unsigned& p1, unsigned& p2, unsigned& p3) {
  unsigned ux = __float_as_uint(x), uy = __float_as_uint(y);
  unsigned x1 = ux & 0xFFFF0000u, y1 = uy & 0xFFFF0000u;
  float rx = x - __uint_as_float(x1), ry = y - __uint_as_float(y1);
  unsigned x2 = __float_as_uint(rx) & 0xFFFF0000u;
  unsigned y2 = __float_as_uint(ry) & 0xFFFF0000u;
  float sx = rx - __uint_as_float(x2), sy = ry - __uint_as_float(y2);
  p1 = (x1 >> 16) | y1;
  p2 = (x2 >> 16) | y2;
  p3 = (__float_as_uint(sx) >> 16) | (__float_as_uint(sy) & 0xFFFF0000u);
}

// LDS swizzle for [128][32]-bf16 tiles (write & read sides; 0 conflicts, r6/r9)
__device__ inline int swz(int e) { return e ^ (((e >> 6) & 3) << 3); }

// ---------------- small per-token kernels ----------------

__global__ void gather_k(const int* __restrict__ ids, const float* __restrict__ emb,
                         float* __restrict__ h) {
  int t = blockIdx.x;
  int id = ids[t];
  const float4* src = (const float4*)(emb + (size_t)id * kH);
  float4* dst = (float4*)(h + (size_t)t * kH);
  dst[threadIdx.x] = src[threadIdx.x];
}

__global__ void router_k(const float* __restrict__ h, const float* __restrict__ rw,
                         const float* __restrict__ rb, float* __restrict__ logits) {
  int t = blockIdx.x;
  int lg = threadIdx.x & 31;
  int e = threadIdx.x >> 5;
  const float* hr = h + (size_t)t * kH;
  const float* wr = rw + (size_t)e * kH;
  float p = 0.f;
  for (int k = lg * 4; k < kH; k += 128) {
    float4 a = *(const float4*)(hr + k);
    float4 b = *(const float4*)(wr + k);
    p += a.x * b.x + a.y * b.y + a.z * b.z + a.w * b.w;
  }
  for (int o = 16; o > 0; o >>= 1) p += __shfl_down(p, o, 32);
  if (lg == 0) logits[t * kE + e] = p + rb[e];
}

__global__ void topk_k(const float* __restrict__ logits, int* __restrict__ sel,
                       float* __restrict__ w_sum, int* __restrict__ cnt) {
  int t = blockIdx.x * blockDim.x + threadIdx.x;
  if (t >= kT) return;
  float v[8];
#pragma unroll
  for (int e = 0; e < 8; e++) v[e] = logits[t * 8 + e];
  int e1 = 0; float v1 = v[0];
#pragma unroll
  for (int e = 1; e < 8; e++) if (v[e] > v1) { v1 = v[e]; e1 = e; }
  int e2 = -1; float v2 = -3.4e38f;
#pragma unroll
  for (int e = 0; e < 8; e++) if (e != e1 && v[e] > v2) { v2 = v[e]; e2 = e; }
  float z = expf(v2 - v1);
  float w1 = 1.f / (1.f + z);
  float w2 = z * w1;
  sel[t * 2] = e1;
  sel[t * 2 + 1] = e2;
  atomicAdd(&w_sum[e1], w1);
  atomicAdd(&w_sum[e2], w2);
  atomicAdd(&cnt[e1], 1);
  atomicAdd(&cnt[e2], 1);
}

// builds 128-ALIGNED expert offsets + block table
__global__ void finalize_k(const int* __restrict__ cnt, const float* __restrict__ w_sum,
                           float* __restrict__ scal, int* __restrict__ off,
                           int* __restrict__ fill, float* __restrict__ aux,
                           int* __restrict__ blk_e, int* __restrict__ blk_m) {
  if (threadIdx.x == 0) {
    int o = 0;
    float a = 0.f;
    for (int e = 0; e < 8; e++) {
      off[e] = o;
      o += (cnt[e] + 127) & ~127;   // 128-aligned padding
      fill[e] = 0;
      int c = cnt[e];
      scal[e] = c > 0 ? w_sum[e] / (float)c : 0.f;
      float d = (float)c - 256.f;
      a += d * d;
    }
    aux[0] += 0.01f * (a * 0.125f);
    int nb = 0;
    for (int e = 0; e < 8; e++)
      for (int m = 0; m < cnt[e]; m += 128) { blk_e[nb] = e; blk_m[nb] = m; nb++; }
    for (int i = nb; i < kNB; i++) { blk_e[i] = -1; blk_m[i] = 0; }
  }
}

// records each token's compact-slot position for the combine step
__global__ void scatter_k(const int* __restrict__ sel, const int* __restrict__ off,
                          int* __restrict__ fill, int* __restrict__ list,
                          int* __restrict__ pos) {
  int t = blockIdx.x * blockDim.x + threadIdx.x;
  if (t >= kT) return;
#pragma unroll
  for (int s = 0; s < 2; s++) {
    int e = sel[t * 2 + s];
    int p = atomicAdd(&fill[e], 1);
    int slot = off[e] + p;
    list[slot] = t;
    pos[t * 2 + s] = slot;
  }
}

// out[t] = LayerNorm( sum_{s in 2} sum_{kc in 4} c_comp[kc][pos[t,s]] ) -> h (f32)
// AND h_bf (bf16, RNE) -- fused cvt
__global__ void combine_ln_k(const float* __restrict__ ccomp, const int* __restrict__ pos,
                             float* __restrict__ h, unsigned short* __restrict__ hbf,
                             const float* __restrict__ g, const float* __restrict__ b) {
  int t = blockIdx.x;
  int s0 = pos[t * 2], s1 = pos[t * 2 + 1];
  int k = threadIdx.x * 4;
  float4 v = {0.f, 0.f, 0.f, 0.f};
#pragma unroll
  for (int kc = 0; kc < kSK; kc++) {
    const float* base = ccomp + (size_t)kc * ((size_t)kRp * kH);
    float4 a = *(const float4*)(base + (size_t)s0 * kH + k);
    float4 c = *(const float4*)(base + (size_t)s1 * kH + k);
    v.x += a.x + c.x; v.y += a.y + c.y; v.z += a.z + c.z; v.w += a.w + c.w;
  }
  float s = v.x + v.y + v.z + v.w;
  float sq = v.x * v.x + v.y * v.y + v.z * v.z + v.w * v.w;
  for (int o = 32; o > 0; o >>= 1) {
    s += __shfl_down(s, o);
    sq += __shfl_down(sq, o);
  }
  __shared__ float ss[4], sqs[4];
  int wave = threadIdx.x >> 6, lane = threadIdx.x & 63;
  if (lane == 0) { ss[wave] = s; sqs[wave] = sq; }
  __syncthreads();
  __shared__ float mu, inv;
  if (threadIdx.x == 0) {
    float st = ss[0] + ss[1] + ss[2] + ss[3];
    float sqt = sqs[0] + sqs[1] + sqs[2] + sqs[3];
    float m = st / (float)kH;
    float var = sqt / (float)kH - m * m;
    mu = m;
    inv = 1.f / sqrtf(var + 1e-5f);
  }
  __syncthreads();
  float4 gg = *(const float4*)(g + k);
  float4 bb = *(const float4*)(b + k);
  float4 o;
  o.x = (v.x - mu) * inv * gg.x + bb.x;
  o.y = (v.y - mu) * inv * gg.y + bb.y;
  o.z = (v.z - mu) * inv * gg.z + bb.z;
  o.w = (v.w - mu) * inv * gg.w + bb.w;
  *(float4*)(h + (size_t)t * kH + k) = o;
  uint2 pk;
  pk.x = (unsigned)f2bf(o.x) | ((unsigned)f2bf(o.y) << 16);
  pk.y = (unsigned)f2bf(o.z) | ((unsigned)f2bf(o.w) << 16);
  *(uint2*)(hbf + (size_t)t * kH + k) = pk;
}

__global__ void aux_write_k(float* __restrict__ out, const float* __restrict__ aux) {
  out[(size_t)kT * kV] = aux[0];
}

// ---------------- bf16x3 split-precision MFMA GEMM (layer-1 FFN, f32-grade) ----------
// 8-WAVE variant: 512 threads, wave grid 2(m)x4(n), each wave 64x32 (4x2 frags).
// Same 128x128 tile, same 48KB swizzled LDS, same dec values, same per-acc term
// order and K-order -> bit-identical results. Per-thread staging/dec/writes halve;
// resident waves/SIMD rise ~2x (latency hiding across the 2 barriers per K-step).
// MODE 0: fc1 (A rows via token list, GELU -> f32 a_buf)
// MODE 1: fc2 (A = compact rows, split-K=4, scal*(acc[+bias]) -> per-chunk compact)
template <int MODE>
__launch_bounds__(512)
__global__ void tgemm_k(const float* __restrict__ Abase, int ldA,
                        const float* __restrict__ Bbase,
                        const float* __restrict__ bias,
                        float* __restrict__ Cout,
                        const int* __restrict__ list,
                        const int* __restrict__ off,
                        const int* __restrict__ cnt,
                        const float* __restrict__ scal,
                        const int* __restrict__ blk_e,
                        const int* __restrict__ blk_m,
                        int N, int Kd) {
  const int e = blk_e[blockIdx.x];
  if (e < 0) return;
  const int m0 = blk_m[blockIdx.x];
  const int M = cnt[e];
  int nb = blockIdx.y, kc = 0;
  if constexpr (MODE == 1) { nb = blockIdx.y >> 2; kc = blockIdx.y & 3; }
  const int n0 = nb * 128;
  const int roff = off[e];
  const float* Bp = Bbase + (size_t)e * (size_t)N * (size_t)Kd;
  const float* be = bias + (size_t)e * (size_t)N;
  const int kBeg = (MODE == 1) ? kc * (Kd >> 2) : 0;
  const int kEnd = (MODE == 1) ? kBeg + (Kd >> 2) : Kd;

  __shared__ __align__(16) unsigned short As[3][128 * 32];
  __shared__ __align__(16) unsigned short Bs[3][128 * 32];

  const int tid = threadIdx.x, w = tid >> 6, l = tid & 63;

  // staging: thread covers tile-row tid>>2, col-quarter (tid&3)*8 (8 f32 each)
  const int srow = tid >> 2, scol = (tid & 3) * 8;
  int gr = m0 + srow; if (gr > M - 1) gr = M - 1;
  long arow;
  if constexpr (MODE == 0) arow = list[roff + gr];
  else arow = roff + gr;
  const float* asrc = Abase + arow * (long)ldA + scol;
  const float* bsrc = Bp + (size_t)(n0 + srow) * (size_t)Kd + scol;
  const int s0 = swz(srow * 32 + scol);

  // wave -> output mapping: 2(m) x 4(n); wave tile 64m x 32n
  const int wm = w >> 2, wn = w & 3;
  const int fr = l & 15, fk = (l >> 4) * 8;

  f32x4 acc[4][2] = {};

  float4 rva[2], rvb[2];
  unsigned qa1[4], qa2[4], qa3[4], qb1[4], qb2[4], qb3[4];

#define LOADT(K0)                                   \
  _Pragma("unroll") for (int i = 0; i < 2; i++) {   \
    rva[i] = *(const float4*)(asrc + (K0) + i * 4); \
    rvb[i] = *(const float4*)(bsrc + (K0) + i * 4); \
  }

#define DECALL()                                               \
  {                                                            \
    float xa[8], xb[8];                                        \
    *(float4*)&xa[0] = rva[0]; *(float4*)&xa[4] = rva[1];      \
    *(float4*)&xb[0] = rvb[0]; *(float4*)&xb[4] = rvb[1];      \
    _Pragma("unroll") for (int i = 0; i < 4; i++) {            \
      dec2(xa[2 * i], xa[2 * i + 1], qa1[i], qa2[i], qa3[i]);  \
      dec2(xb[2 * i], xb[2 * i + 1], qb1[i], qb2[i], qb3[i]);  \
    }                                                          \
  }

  LOADT(kBeg);
  DECALL();

  for (int k0 = kBeg; k0 < kEnd; k0 += 32) {
    // serial segment: 6 LDS writes of the pre-decomposed tile
    *(uint4*)&As[0][s0] = *(uint4*)&qa1[0];
    *(uint4*)&As[1][s0] = *(uint4*)&qa2[0];
    *(uint4*)&As[2][s0] = *(uint4*)&qa3[0];
    *(uint4*)&Bs[0][s0] = *(uint4*)&qb1[0];
    *(uint4*)&Bs[1][s0] = *(uint4*)&qb2[0];
    *(uint4*)&Bs[2][s0] = *(uint4*)&qb3[0];
    __syncthreads();
    const bool more = (k0 + 32 < kEnd);
    if (more) LOADT(k0 + 32);  // global issue; returns under MFMA phase

    bf16x8 bf1[2], bf2[2], bf3[2];
#pragma unroll
    for (int bn = 0; bn < 2; bn++) {
      int se = swz((wn * 32 + bn * 16 + fr) * 32 + fk);
      bf1[bn] = *(const bf16x8*)(&Bs[0][se]);
      bf2[bn] = *(const bf16x8*)(&Bs[1][se]);
      bf3[bn] = *(const bf16x8*)(&Bs[2][se]);
    }
#pragma unroll
    for (int am = 0; am < 4; am++) {
      int se = swz((wm * 64 + am * 16 + fr) * 32 + fk);
      bf16x8 a1 = *(const bf16x8*)(&As[0][se]);
      bf16x8 a2 = *(const bf16x8*)(&As[1][se]);
      bf16x8 a3 = *(const bf16x8*)(&As[2][se]);
      // per-acc term order unchanged: a3b1, a2b2, a1b3, a2b1, a1b2, a1b1
      f32x4 c0 = acc[am][0], c1 = acc[am][1];
#define TERM(AF, BARR)                                                        \
      c0 = __builtin_amdgcn_mfma_f32_16x16x32_bf16(AF, BARR[0], c0, 0, 0, 0); \
      c1 = __builtin_amdgcn_mfma_f32_16x16x32_bf16(AF, BARR[1], c1, 0, 0, 0);
      TERM(a3, bf1)
      TERM(a2, bf2)
      TERM(a1, bf3)
      TERM(a2, bf1)
      TERM(a1, bf2)
      TERM(a1, bf1)
#undef TERM
      acc[am][0] = c0; acc[am][1] = c1;
    }
    if (more) DECALL();  // VALU stream; compiler interleaves with MFMA above
    __syncthreads();
  }
#undef LOADT
#undef DECALL

  // C/D layout: col = lane&15, row = (lane>>4)*4 + j  (m89/m91-verified)
  const int r0 = (l >> 4) * 4, cc = l & 15;
#pragma unroll
  for (int am = 0; am < 4; am++) {
#pragma unroll
    for (int bn = 0; bn < 2; bn++) {
      int gn = n0 + wn * 32 + bn * 16 + cc;
      float bv;
      if constexpr (MODE == 1) bv = (kc == 0) ? be[gn] : 0.f;
      else bv = be[gn];
#pragma unroll
      for (int j = 0; j < 4; j++) {
        int gm = m0 + wm * 64 + am * 16 + r0 + j;
        if (gm >= M) continue;
        float v = acc[am][bn][j] + bv;
        if constexpr (MODE == 0) {
          float g = 0.5f * v * (1.f + erff(v * 0.70710678118654752f));
          Cout[(size_t)(roff + gm) * (size_t)N + gn] = g;
        } else {
          Cout[(size_t)kc * ((size_t)kRp * kH) + (size_t)(roff + gm) * (size_t)N + gn] =
              scal[e] * v;
        }
      }
    }
  }
}

// ---------------- layer-2 GEMM: A (bf16) via global_load_lds, B (f32) cvt-staged ----
// MODE 0: fc1-l2 (A = h_bf rows via list gather; GELU -> bf16 a_bf)
// MODE 1: fc2-l2 (A = a_bf compact rows; split-K=4; scal*(acc[+bias]) -> c_comp f32)
template <int MODE>
__launch_bounds__(256)
__global__ void wfgemm_k(const unsigned short* __restrict__ Abase, int ldA,
                         const float* __restrict__ Bbase,
                         const float* __restrict__ bias,
                         float* __restrict__ Cout,
                         unsigned short* __restrict__ Cbf,
                         const int* __restrict__ list,
                         const int* __restrict__ off,
                         const int* __restrict__ cnt,
                         const float* __restrict__ scal,
                         const int* __restrict__ blk_e,
                         const int* __restrict__ blk_m,
                         int N, int Kd) {
  const int e = blk_e[blockIdx.x];
  if (e < 0) return;
  const int m0 = blk_m[blockIdx.x];
  const int M = cnt[e];
  int nb = blockIdx.y, kc = 0;
  if constexpr (MODE == 1) { nb = blockIdx.y >> 2; kc = blockIdx.y & 3; }
  const int n0 = nb * 128;
  const int roff = off[e];
  const float* Bp = Bbase + (size_t)e * (size_t)N * (size_t)Kd;
  const float* be = bias + (size_t)e * (size_t)N;
  const int kBeg = (MODE == 1) ? kc * (Kd >> 2) : 0;
  const int kEnd = (MODE == 1) ? kBeg + (Kd >> 2) : Kd;

  __shared__ __align__(16) unsigned short As[128 * 64];
  __shared__ __align__(16) unsigned short Bs[128 * 64];

  const int tid = threadIdx.x, w = tid >> 6, l = tid & 63;

  const unsigned short* asrc[4];
  const float* bsrc[4];
#pragma unroll
  for (int i = 0; i < 4; i++) {
    int r = w * 8 + i * 32 + (l >> 3);
    int gr = m0 + r; if (gr > M - 1) gr = M - 1;
    long grow;
    if constexpr (MODE == 0) grow = list[roff + gr];
    else grow = roff + gr;
    asrc[i] = Abase + grow * (long)ldA + (l & 7) * 8;
    bsrc[i] = Bp + (size_t)(n0 + r) * (size_t)Kd + (l & 7) * 8;
  }
  const int ldstB = w * 512 + (l >> 3) * 64 + (((l & 7) ^ (l >> 3)) * 8);

  f32x4 acc[4][4] = {};
  const int wm = w >> 1, wn = w & 1;
  const int fr = l & 15, fk = (l >> 4) * 8;
  const int col0 = (((l >> 4) + 0) ^ (l & 7)) * 8;
  const int col1 = (((l >> 4) + 4) ^ (l & 7)) * 8;

  float4 rb[4][2];
#define LOADB(K0)                                            \
  _Pragma("unroll") for (int i = 0; i < 4; i++) {            \
    rb[i][0] = *(const float4*)(bsrc[i] + (K0));             \
    rb[i][1] = *(const float4*)(bsrc[i] + (K0) + 4);         \
  }

  LOADB(kBeg);

  for (int k0 = kBeg; k0 < kEnd; k0 += 64) {
#pragma unroll
    for (int i = 0; i < 4; i++) {
      __builtin_amdgcn_global_load_lds(
          (const __attribute__((address_space(1))) unsigned int*)(const void*)(asrc[i] + k0),
          (__attribute__((address_space(3))) unsigned int*)(void*)(As + w * 512 + i * 2048),
          16, 0, 0);
      uint4 pb;
      pb.x = cvtpk(rb[i][0].x, rb[i][0].y);
      pb.y = cvtpk(rb[i][0].z, rb[i][0].w);
      pb.z = cvtpk(rb[i][1].x, rb[i][1].y);
      pb.w = cvtpk(rb[i][1].z, rb[i][1].w);
      *(uint4*)(Bs + ldstB + i * 2048) = pb;
    }
    __syncthreads();  // drains A gloads + B writes
    if (k0 + 64 < kEnd) LOADB(k0 + 64);  // B prefetch hides HBM under MFMA
#pragma unroll
    for (int ks = 0; ks < 2; ks++) {
      const int ck = ks ? col1 : col0;
      bf16x8 af[4], bfr[4];
#pragma unroll
      for (int am = 0; am < 4; am++)
        af[am] = *(const bf16x8*)(As + (wm * 64 + am * 16 + fr) * 64 + ks * 32 + fk);
#pragma unroll
      for (int bn = 0; bn < 4; bn++)
        bfr[bn] = *(const bf16x8*)(Bs + (wn * 64 + bn * 16 + fr) * 64 + ck);
#pragma unroll
      for (int am = 0; am < 4; am++)
#pragma unroll
        for (int bn = 0; bn < 4; bn++)
          acc[am][bn] = __builtin_amdgcn_mfma_f32_16x16x32_bf16(af[am], bfr[bn], acc[am][bn], 0, 0, 0);
    }
    __syncthreads();
  }
#undef LOADB

  const int r0 = (l >> 4) * 4, cc = l & 15;
#pragma unroll
  for (int am = 0; am < 4; am++) {
#pragma unroll
    for (int bn = 0; bn < 4; bn++) {
      int gn = n0 + wn * 64 + bn * 16 + cc;
      float bv;
      if constexpr (MODE == 1) bv = (kc == 0) ? be[gn] : 0.f;
      else bv = be[gn];
#pragma unroll
      for (int j = 0; j < 4; j++) {
        int gm = m0 + wm * 64 + am * 16 + r0 + j;
        if (gm >= M) continue;
        float v = acc[am][bn][j] + bv;
        if constexpr (MODE == 0) {
          float g = 0.5f * v * (1.f + erff(v * 0.70710678118654752f));
          Cbf[(size_t)(roff + gm) * (size_t)N + gn] = f2bf(g);
        } else {
          Cout[(size_t)kc * ((size_t)kRp * kH) + (size_t)(roff + gm) * (size_t)N + gn] =
              scal[e] * v;
        }
      }
    }
  }
}

// ---------------- head GEMM: A (h_bf) via global_load_lds, B (head_w f32) cvt-staged
__launch_bounds__(256)
__global__ void hgemm_k(const unsigned short* __restrict__ hbf,
                        const float* __restrict__ Bw,
                        const float* __restrict__ bias,
                        float* __restrict__ Cout) {
  int bx = blockIdx.x, by = blockIdx.y;
  {
    int lin = by * gridDim.x + bx;
    int nwg = gridDim.x * gridDim.y;
    int q = nwg >> 3, r = nwg & 7;
    int xcd = lin & 7, idx = lin >> 3;
    int swzb = (xcd < r ? xcd * (q + 1) : r * (q + 1) + (xcd - r) * q) + idx;
    bx = swzb % gridDim.x;
    by = swzb / gridDim.x;
  }
  const int m0 = bx * 128;
  const int n0 = by * 128;

  __shared__ __align__(16) unsigned short As[128 * 64];
  __shared__ __align__(16) unsigned short Bs[128 * 64];

  const int tid = threadIdx.x, w = tid >> 6, l = tid & 63;

  const unsigned short* asrc[4];
  const float* bsrc[4];
#pragma unroll
  for (int i = 0; i < 4; i++) {
    int r = w * 8 + i * 32 + (l >> 3);
    asrc[i] = hbf + (size_t)(m0 + r) * kH + (l & 7) * 8;
    bsrc[i] = Bw + (size_t)(n0 + r) * kH + (l & 7) * 8;
  }
  const int ldstB = w * 512 + (l >> 3) * 64 + (((l & 7) ^ (l >> 3)) * 8);

  f32x4 acc[4][4] = {};
  const int wm = w >> 1, wn = w & 1;
  const int fr = l & 15, fk = (l >> 4) * 8;
  const int col0 = (((l >> 4) + 0) ^ (l & 7)) * 8;
  const int col1 = (((l >> 4) + 4) ^ (l & 7)) * 8;

  float4 rb[4][2];
#define LOADB(K0)                                            \
  _Pragma("unroll") for (int i = 0; i < 4; i++) {            \
    rb[i][0] = *(const float4*)(bsrc[i] + (K0));             \
    rb[i][1] = *(const float4*)(bsrc[i] + (K0) + 4);         \
  }

  LOADB(0);

  for (int k0 = 0; k0 < kH; k0 += 64) {
#pragma unroll
    for (int i = 0; i < 4; i++) {
      __builtin_amdgcn_global_load_lds(
          (const __attribute__((address_space(1))) unsigned int*)(const void*)(asrc[i] + k0),
          (__attribute__((address_space(3))) unsigned int*)(void*)(As + w * 512 + i * 2048),
          16, 0, 0);
      uint4 pb;
      pb.x = cvtpk(rb[i][0].x, rb[i][0].y);
      pb.y = cvtpk(rb[i][0].z, rb[i][0].w);
      pb.z = cvtpk(rb[i][1].x, rb[i][1].y);
      pb.w = cvtpk(rb[i][1].z, rb[i][1].w);
      *(uint4*)(Bs + ldstB + i * 2048) = pb;
    }
    __syncthreads();
    if (k0 + 64 < kH) LOADB(k0 + 64);
#pragma unroll
    for (int ks = 0; ks < 2; ks++) {
      const int ck = ks ? col1 : col0;
      bf16x8 af[4], bfr[4];
#pragma unroll
      for (int am = 0; am < 4; am++)
        af[am] = *(const bf16x8*)(As + (wm * 64 + am * 16 + fr) * 64 + ks * 32 + fk);
#pragma unroll
      for (int bn = 0; bn < 4; bn++)
        bfr[bn] = *(const bf16x8*)(Bs + (wn * 64 + bn * 16 + fr) * 64 + ck);
#pragma unroll
      for (int am = 0; am < 4; am++)
#pragma unroll
        for (int bn = 0; bn < 4; bn++)
          acc[am][bn] = __builtin_amdgcn_mfma_f32_16x16x32_bf16(af[am], bfr[bn], acc[am][bn], 0, 0, 0);
    }
    __syncthreads();
  }
#undef LOADB

  const int r0 = (l >> 4) * 4, cc = l & 15;
#pragma unroll
  for (int am = 0; am < 4; am++) {
#pragma unroll
    for (int bn = 0; bn < 4; bn++) {
      int gn = n0 + wn * 64 + bn * 16 + cc;
      float bv = bias[gn];
#pragma unroll
      for (int j = 0; j < 4; j++) {
        int gm = m0 + wm * 64 + am * 16 + r0 + j;
        Cout[(size_t)gm * (size_t)kV + gn] = acc[am][bn][j] + bv;
      }
    }
  }
}

// ---------------- launch ----------------

extern "C" void kernel_launch(void* const* d_in, const int* in_sizes, int n_in,
                              void* d_out, int out_size, void* d_ws, size_t ws_size,
                              hipStream_t stream) {
  (void)in_sizes; (void)n_in; (void)out_size; (void)ws_size;
  const int* ids = (const int*)d_in[0];
  const float* emb = (const float*)d_in[1];
  const float* router_w = (const float*)d_in[2];
  const float* router_b = (const float*)d_in[3];
  const float* fc1_w = (const float*)d_in[4];
  const float* fc1_b = (const float*)d_in[5];
  const float* fc2_w = (const float*)d_in[6];
  const float* fc2_b = (const float*)d_in[7];
  const float* ln_g = (const float*)d_in[8];
  const float* ln_b = (const float*)d_in[9];
  const float* head_w = (const float*)d_in[10];
  const float* head_b = (const float*)d_in[11];
  float* out = (float*)d_out;

  // --- workspace layout (~13 MB) ---
  float* ws_f = (float*)d_ws;
  float* h       = ws_f;                          // kT*kH f32
  float* logits  = h + (size_t)kT * kH;           // kT*kE
  float* w_sum   = logits + (size_t)kT * kE;      // kE
  float* scal    = w_sum + kE;                    // kE
  float* aux     = scal + kE;                     // 1
  int* sel  = (int*)(aux + 1);                    // kT*2
  int* cnt  = sel + 2 * kT;                       // kE
  int* off  = cnt + kE;                           // kE
  int* fill = off + kE;                           // kE
  int* list = fill + kE;                          // kRp
  int* pos  = list + kRp;                         // kT*2
  int* blk_e = pos + 2 * kT;                      // kNB
  int* blk_m = blk_e + kNB;                       // kNB
  unsigned short* h_bf = (unsigned short*)(blk_m + kNB);  // kT*kH bf16 (4.2 MB)

  // --- d_out scratch (head overwrites everything at the end) ---
  float* a_f32  = out;                                    // kRp*kI f32
  float* c_comp = a_f32 + (size_t)kRp * kI;               // kSK*kRp*kH f32
  unsigned short* a_bf = (unsigned short*)out;            // kRp*kI bf16

  hipMemsetAsync(aux, 0, sizeof(float), stream);
  gather_k<<<kT, 256, 0, stream>>>(ids, emb, h);

  for (int l = 0; l < kL; l++) {
    hipMemsetAsync(w_sum, 0, kE * sizeof(float), stream);
    hipMemsetAsync(cnt, 0, kE * sizeof(int), stream);
    router_k<<<kT, 256, 0, stream>>>(h, router_w + (size_t)l * kE * kH,
                                     router_b + (size_t)l * kE, logits);
    topk_k<<<kT / 256, 256, 0, stream>>>(logits, sel, w_sum, cnt);
    finalize_k<<<1, 64, 0, stream>>>(cnt, w_sum, scal, off, fill, aux, blk_e, blk_m);
    scatter_k<<<kT / 256, 256, 0, stream>>>(sel, off, fill, list, pos);

    if (l == 0) {
      // layer-1: bf16x3 split MFMA (8-wave variant for TLP; bit-identical math)
      tgemm_k<0><<<dim3(kNB, kI / 128), 512, 0, stream>>>(
          h, kH, fc1_w + (size_t)l * kE * kI * kH, fc1_b + (size_t)l * kE * kI,
          a_f32, list, off, cnt, scal, blk_e, blk_m, kI, kH);
      tgemm_k<1><<<dim3(kNB, (kH / 128) * kSK), 512, 0, stream>>>(
          a_f32, kI, fc2_w + (size_t)l * kE * kH * kI, fc2_b + (size_t)l * kE * kH,
          c_comp, list, off, cnt, scal, blk_e, blk_m, kH, kI);
    } else {
      // layer-2: A bf16 gload_lds + B f32 cvt-staged (no weight cvt passes)
      wfgemm_k<0><<<dim3(kNB, kI / 128), 256, 0, stream>>>(
          h_bf, kH, fc1_w + (size_t)l * kE * kI * kH, fc1_b + (size_t)l * kE * kI,
          nullptr, a_bf, list, off, cnt, scal, blk_e, blk_m, kI, kH);
      wfgemm_k<1><<<dim3(kNB, (kH / 128) * kSK), 256, 0, stream>>>(
          a_bf, kI, fc2_w + (size_t)l * kE * kH * kI, fc2_b + (size_t)l * kE * kH,
          c_comp, nullptr, list, off, cnt, scal, blk_e, blk_m, kH, kI);
    }

    combine_ln_k<<<kT, 256, 0, stream>>>(c_comp, pos, h, h_bf,
                                         ln_g + (size_t)l * kH, ln_b + (size_t)l * kH);
  }

  // head: A = h_bf via gload_lds; B = head_w f32 cvt-staged with reg prefetch
  hgemm_k<<<dim3(kT / 128, kV / 128), 256, 0, stream>>>(h_bf, head_w, head_b, out);

  aux_write_k<<<1, 1, 0, stream>>>(out, aux);
}

// Round 17
// 1159.806 us; speedup vs baseline: 1.2238x; 1.2238x over previous
//
#include <hip/hip_runtime.h>
#include <math.h>

// Problem constants
constexpr int kT = 2048;   // tokens (B*S)
constexpr int kH = 1024;   // hidden
constexpr int kI = 4096;   // ffn inner
constexpr int kE = 8;      // experts
constexpr int kV = 32000;  // vocab
constexpr int kL = 2;      // layers
constexpr int kR = 4096;   // total routed rows = K*T
constexpr int kRp = 5120;  // padded compact rows (off[e] 128-aligned)
constexpr int kSK = 4;     // fc2 split-K chunks
constexpr int kNB = kR / 128 + kE - 1;  // 39: max active m-blocks across experts

typedef __attribute__((ext_vector_type(4))) float f32x4;
typedef __attribute__((ext_vector_type(8))) short bf16x8;

// f32 pair -> packed bf16x2 (gfx950 v_cvt_pk_bf16_f32; RNE — same as f2bf)
__device__ inline unsigned cvtpk(float lo, float hi) {
  unsigned r;
  asm("v_cvt_pk_bf16_f32 %0, %1, %2" : "=v"(r) : "v"(lo), "v"(hi));
  return r;
}

__device__ inline unsigned short f2bf(float x) {
  union { float f; unsigned u; } c; c.f = x;
  unsigned u = c.u;
  u += 0x7FFFu + ((u >> 16) & 1u);  // RNE
  return (unsigned short)(u >> 16);
}

// bf16x2 exact-truncation decompose of an f32 pair, packed per level.
// x = x1 + r; x1 = trunc16(x) (exact); x2 = trunc16(r). Dropped cross terms
// (a2b2, a1b3, a3b1) are ~2^-16 relative -> layer-1 rel err ~1.5e-5 (router-safe).
__device__ inline void dec2b(float x, float y, unsigned& p1, unsigned& p2) {
  unsigned ux = __float_as_uint(x), uy = __float_as_uint(y);
  unsigned x1 = ux & 0xFFFF0000u, y1 = uy & 0xFFFF0000u;
  float rx = x - __uint_as_float(x1), ry = y - __uint_as_float(y1);
  p1 = (x1 >> 16) | y1;
  p2 = (__float_as_uint(rx) >> 16) | (__float_as_uint(ry) & 0xFFFF0000u);
}

// LDS swizzle for [128][32]-bf16 tiles (write & read sides; 0 conflicts, r6/r9)
__device__ inline int swz(int e) { return e ^ (((e >> 6) & 3) << 3); }

// ---------------- small per-token kernels ----------------

__global__ void gather_k(const int* __restrict__ ids, const float* __restrict__ emb,
                         float* __restrict__ h) {
  int t = blockIdx.x;
  int id = ids[t];
  const float4* src = (const float4*)(emb + (size_t)id * kH);
  float4* dst = (float4*)(h + (size_t)t * kH);
  dst[threadIdx.x] = src[threadIdx.x];
}

__global__ void router_k(const float* __restrict__ h, const float* __restrict__ rw,
                         const float* __restrict__ rb, float* __restrict__ logits) {
  int t = blockIdx.x;
  int lg = threadIdx.x & 31;
  int e = threadIdx.x >> 5;
  const float* hr = h + (size_t)t * kH;
  const float* wr = rw + (size_t)e * kH;
  float p = 0.f;
  for (int k = lg * 4; k < kH; k += 128) {
    float4 a = *(const float4*)(hr + k);
    float4 b = *(const float4*)(wr + k);
    p += a.x * b.x + a.y * b.y + a.z * b.z + a.w * b.w;
  }
  for (int o = 16; o > 0; o >>= 1) p += __shfl_down(p, o, 32);
  if (lg == 0) logits[t * kE + e] = p + rb[e];
}

__global__ void topk_k(const float* __restrict__ logits, int* __restrict__ sel,
                       float* __restrict__ w_sum, int* __restrict__ cnt) {
  int t = blockIdx.x * blockDim.x + threadIdx.x;
  if (t >= kT) return;
  float v[8];
#pragma unroll
  for (int e = 0; e < 8; e++) v[e] = logits[t * 8 + e];
  int e1 = 0; float v1 = v[0];
#pragma unroll
  for (int e = 1; e < 8; e++) if (v[e] > v1) { v1 = v[e]; e1 = e; }
  int e2 = -1; float v2 = -3.4e38f;
#pragma unroll
  for (int e = 0; e < 8; e++) if (e != e1 && v[e] > v2) { v2 = v[e]; e2 = e; }
  float z = expf(v2 - v1);
  float w1 = 1.f / (1.f + z);
  float w2 = z * w1;
  sel[t * 2] = e1;
  sel[t * 2 + 1] = e2;
  atomicAdd(&w_sum[e1], w1);
  atomicAdd(&w_sum[e2], w2);
  atomicAdd(&cnt[e1], 1);
  atomicAdd(&cnt[e2], 1);
}

// builds 128-ALIGNED expert offsets + block table
__global__ void finalize_k(const int* __restrict__ cnt, const float* __restrict__ w_sum,
                           float* __restrict__ scal, int* __restrict__ off,
                           int* __restrict__ fill, float* __restrict__ aux,
                           int* __restrict__ blk_e, int* __restrict__ blk_m) {
  if (threadIdx.x == 0) {
    int o = 0;
    float a = 0.f;
    for (int e = 0; e < 8; e++) {
      off[e] = o;
      o += (cnt[e] + 127) & ~127;   // 128-aligned padding
      fill[e] = 0;
      int c = cnt[e];
      scal[e] = c > 0 ? w_sum[e] / (float)c : 0.f;
      float d = (float)c - 256.f;
      a += d * d;
    }
    aux[0] += 0.01f * (a * 0.125f);
    int nb = 0;
    for (int e = 0; e < 8; e++)
      for (int m = 0; m < cnt[e]; m += 128) { blk_e[nb] = e; blk_m[nb] = m; nb++; }
    for (int i = nb; i < kNB; i++) { blk_e[i] = -1; blk_m[i] = 0; }
  }
}

// records each token's compact-slot position for the combine step
__global__ void scatter_k(const int* __restrict__ sel, const int* __restrict__ off,
                          int* __restrict__ fill, int* __restrict__ list,
                          int* __restrict__ pos) {
  int t = blockIdx.x * blockDim.x + threadIdx.x;
  if (t >= kT) return;
#pragma unroll
  for (int s = 0; s < 2; s++) {
    int e = sel[t * 2 + s];
    int p = atomicAdd(&fill[e], 1);
    int slot = off[e] + p;
    list[slot] = t;
    pos[t * 2 + s] = slot;
  }
}

// out[t] = LayerNorm( sum_{s in 2} sum_{kc in 4} c_comp[kc][pos[t,s]] ) -> h (f32)
// AND h_bf (bf16, RNE) -- fused cvt
__global__ void combine_ln_k(const float* __restrict__ ccomp, const int* __restrict__ pos,
                             float* __restrict__ h, unsigned short* __restrict__ hbf,
                             const float* __restrict__ g, const float* __restrict__ b) {
  int t = blockIdx.x;
  int s0 = pos[t * 2], s1 = pos[t * 2 + 1];
  int k = threadIdx.x * 4;
  float4 v = {0.f, 0.f, 0.f, 0.f};
#pragma unroll
  for (int kc = 0; kc < kSK; kc++) {
    const float* base = ccomp + (size_t)kc * ((size_t)kRp * kH);
    float4 a = *(const float4*)(base + (size_t)s0 * kH + k);
    float4 c = *(const float4*)(base + (size_t)s1 * kH + k);
    v.x += a.x + c.x; v.y += a.y + c.y; v.z += a.z + c.z; v.w += a.w + c.w;
  }
  float s = v.x + v.y + v.z + v.w;
  float sq = v.x * v.x + v.y * v.y + v.z * v.z + v.w * v.w;
  for (int o = 32; o > 0; o >>= 1) {
    s += __shfl_down(s, o);
    sq += __shfl_down(sq, o);
  }
  __shared__ float ss[4], sqs[4];
  int wave = threadIdx.x >> 6, lane = threadIdx.x & 63;
  if (lane == 0) { ss[wave] = s; sqs[wave] = sq; }
  __syncthreads();
  __shared__ float mu, inv;
  if (threadIdx.x == 0) {
    float st = ss[0] + ss[1] + ss[2] + ss[3];
    float sqt = sqs[0] + sqs[1] + sqs[2] + sqs[3];
    float m = st / (float)kH;
    float var = sqt / (float)kH - m * m;
    mu = m;
    inv = 1.f / sqrtf(var + 1e-5f);
  }
  __syncthreads();
  float4 gg = *(const float4*)(g + k);
  float4 bb = *(const float4*)(b + k);
  float4 o;
  o.x = (v.x - mu) * inv * gg.x + bb.x;
  o.y = (v.y - mu) * inv * gg.y + bb.y;
  o.z = (v.z - mu) * inv * gg.z + bb.z;
  o.w = (v.w - mu) * inv * gg.w + bb.w;
  *(float4*)(h + (size_t)t * kH + k) = o;
  uint2 pk;
  pk.x = (unsigned)f2bf(o.x) | ((unsigned)f2bf(o.y) << 16);
  pk.y = (unsigned)f2bf(o.z) | ((unsigned)f2bf(o.w) << 16);
  *(uint2*)(hbf + (size_t)t * kH + k) = pk;
}

__global__ void aux_write_k(float* __restrict__ out, const float* __restrict__ aux) {
  out[(size_t)kT * kV] = aux[0];
}

// ---------------- bf16x2 split-precision MFMA GEMM (layer-1 FFN) ----------------
// r14 structure (256 thr, 4 waves, 2-barrier, swizzled LDS, 0 conflicts) with the
// bf16 split reduced 3->2 levels: 3 MFMA terms/frag (a2b1, a1b2, a1b1), 2 LDS
// planes (32 KB), dec and LDS traffic cut ~1/3-1/2. Rel err ~1.5e-5 (router-safe).
// MODE 0: fc1 (A rows via token list, GELU -> f32 a_buf)
// MODE 1: fc2 (A = compact rows, split-K=4, scal*(acc[+bias]) -> per-chunk compact)
template <int MODE>
__launch_bounds__(256)
__global__ void tgemm_k(const float* __restrict__ Abase, int ldA,
                        const float* __restrict__ Bbase,
                        const float* __restrict__ bias,
                        float* __restrict__ Cout,
                        const int* __restrict__ list,
                        const int* __restrict__ off,
                        const int* __restrict__ cnt,
                        const float* __restrict__ scal,
                        const int* __restrict__ blk_e,
                        const int* __restrict__ blk_m,
                        int N, int Kd) {
  const int e = blk_e[blockIdx.x];
  if (e < 0) return;
  const int m0 = blk_m[blockIdx.x];
  const int M = cnt[e];
  int nb = blockIdx.y, kc = 0;
  if constexpr (MODE == 1) { nb = blockIdx.y >> 2; kc = blockIdx.y & 3; }
  const int n0 = nb * 128;
  const int roff = off[e];
  const float* Bp = Bbase + (size_t)e * (size_t)N * (size_t)Kd;
  const float* be = bias + (size_t)e * (size_t)N;
  const int kBeg = (MODE == 1) ? kc * (Kd >> 2) : 0;
  const int kEnd = (MODE == 1) ? kBeg + (Kd >> 2) : Kd;

  __shared__ __align__(16) unsigned short As[2][128 * 32];
  __shared__ __align__(16) unsigned short Bs[2][128 * 32];

  const int tid = threadIdx.x, w = tid >> 6, l = tid & 63;

  // staging: thread covers tile-row tid>>1, col-half (tid&1)*16
  const int srow = tid >> 1, scolh = (tid & 1) * 16;
  int gr = m0 + srow; if (gr > M - 1) gr = M - 1;
  long arow;
  if constexpr (MODE == 0) arow = list[roff + gr];
  else arow = roff + gr;
  const float* asrc = Abase + arow * (long)ldA + scolh;
  const float* bsrc = Bp + (size_t)(n0 + srow) * (size_t)Kd + scolh;
  const int e0 = srow * 32 + scolh;
  const int s0 = swz(e0), s1 = swz(e0 + 8);

  f32x4 acc[4][4] = {};
  const int wm = w >> 1, wn = w & 1;
  const int fr = l & 15, fk = (l >> 4) * 8;

  float4 rva[4], rvb[4];
  unsigned qa1[8], qa2[8], qb1[8], qb2[8];

#define LOADT(K0)                                   \
  _Pragma("unroll") for (int i = 0; i < 4; i++) {   \
    rva[i] = *(const float4*)(asrc + (K0) + i * 4); \
    rvb[i] = *(const float4*)(bsrc + (K0) + i * 4); \
  }

#define DECALL()                                               \
  {                                                            \
    float xa[16], xb[16];                                      \
    *(float4*)&xa[0] = rva[0]; *(float4*)&xa[4] = rva[1];      \
    *(float4*)&xa[8] = rva[2]; *(float4*)&xa[12] = rva[3];     \
    *(float4*)&xb[0] = rvb[0]; *(float4*)&xb[4] = rvb[1];      \
    *(float4*)&xb[8] = rvb[2]; *(float4*)&xb[12] = rvb[3];     \
    _Pragma("unroll") for (int i = 0; i < 8; i++) {            \
      dec2b(xa[2 * i], xa[2 * i + 1], qa1[i], qa2[i]);         \
      dec2b(xb[2 * i], xb[2 * i + 1], qb1[i], qb2[i]);         \
    }                                                          \
  }

  LOADT(kBeg);
  DECALL();

  for (int k0 = kBeg; k0 < kEnd; k0 += 32) {
    // serial segment: just the 8 LDS writes of the pre-decomposed tile
    *(uint4*)&As[0][s0] = *(uint4*)&qa1[0]; *(uint4*)&As[0][s1] = *(uint4*)&qa1[4];
    *(uint4*)&As[1][s0] = *(uint4*)&qa2[0]; *(uint4*)&As[1][s1] = *(uint4*)&qa2[4];
    *(uint4*)&Bs[0][s0] = *(uint4*)&qb1[0]; *(uint4*)&Bs[0][s1] = *(uint4*)&qb1[4];
    *(uint4*)&Bs[1][s0] = *(uint4*)&qb2[0]; *(uint4*)&Bs[1][s1] = *(uint4*)&qb2[4];
    __syncthreads();
    const bool more = (k0 + 32 < kEnd);
    if (more) LOADT(k0 + 32);  // global issue; returns under MFMA phase

    bf16x8 bf1[4], bf2[4];
#pragma unroll
    for (int bn = 0; bn < 4; bn++) {
      int se = swz((wn * 64 + bn * 16 + fr) * 32 + fk);
      bf1[bn] = *(const bf16x8*)(&Bs[0][se]);
      bf2[bn] = *(const bf16x8*)(&Bs[1][se]);
    }
#pragma unroll
    for (int am = 0; am < 4; am++) {
      int se = swz((wm * 64 + am * 16 + fr) * 32 + fk);
      bf16x8 a1 = *(const bf16x8*)(&As[0][se]);
      bf16x8 a2 = *(const bf16x8*)(&As[1][se]);
#pragma unroll
      for (int bn = 0; bn < 4; bn++) {
        f32x4 c = acc[am][bn];
        c = __builtin_amdgcn_mfma_f32_16x16x32_bf16(a2, bf1[bn], c, 0, 0, 0);
        c = __builtin_amdgcn_mfma_f32_16x16x32_bf16(a1, bf2[bn], c, 0, 0, 0);
        c = __builtin_amdgcn_mfma_f32_16x16x32_bf16(a1, bf1[bn], c, 0, 0, 0);
        acc[am][bn] = c;
      }
    }
    if (more) DECALL();  // VALU stream; compiler interleaves with MFMA above
    __syncthreads();
  }
#undef LOADT
#undef DECALL

  // C/D layout: col = lane&15, row = (lane>>4)*4 + j  (m89/m91-verified)
  const int r0 = (l >> 4) * 4, cc = l & 15;
#pragma unroll
  for (int am = 0; am < 4; am++) {
#pragma unroll
    for (int bn = 0; bn < 4; bn++) {
      int gn = n0 + wn * 64 + bn * 16 + cc;
      float bv;
      if constexpr (MODE == 1) bv = (kc == 0) ? be[gn] : 0.f;
      else bv = be[gn];
#pragma unroll
      for (int j = 0; j < 4; j++) {
        int gm = m0 + wm * 64 + am * 16 + r0 + j;
        if (gm >= M) continue;
        float v = acc[am][bn][j] + bv;
        if constexpr (MODE == 0) {
          float g = 0.5f * v * (1.f + erff(v * 0.70710678118654752f));
          Cout[(size_t)(roff + gm) * (size_t)N + gn] = g;
        } else {
          Cout[(size_t)kc * ((size_t)kRp * kH) + (size_t)(roff + gm) * (size_t)N + gn] =
              scal[e] * v;
        }
      }
    }
  }
}

// ---------------- layer-2 GEMM: A (bf16) via global_load_lds, B (f32) cvt-staged ----
// MODE 0: fc1-l2 (A = h_bf rows via list gather; GELU -> bf16 a_bf)
// MODE 1: fc2-l2 (A = a_bf compact rows; split-K=4; scal*(acc[+bias]) -> c_comp f32)
template <int MODE>
__launch_bounds__(256)
__global__ void wfgemm_k(const unsigned short* __restrict__ Abase, int ldA,
                         const float* __restrict__ Bbase,
                         const float* __restrict__ bias,
                         float* __restrict__ Cout,
                         unsigned short* __restrict__ Cbf,
                         const int* __restrict__ list,
                         const int* __restrict__ off,
                         const int* __restrict__ cnt,
                         const float* __restrict__ scal,
                         const int* __restrict__ blk_e,
                         const int* __restrict__ blk_m,
                         int N, int Kd) {
  const int e = blk_e[blockIdx.x];
  if (e < 0) return;
  const int m0 = blk_m[blockIdx.x];
  const int M = cnt[e];
  int nb = blockIdx.y, kc = 0;
  if constexpr (MODE == 1) { nb = blockIdx.y >> 2; kc = blockIdx.y & 3; }
  const int n0 = nb * 128;
  const int roff = off[e];
  const float* Bp = Bbase + (size_t)e * (size_t)N * (size_t)Kd;
  const float* be = bias + (size_t)e * (size_t)N;
  const int kBeg = (MODE == 1) ? kc * (Kd >> 2) : 0;
  const int kEnd = (MODE == 1) ? kBeg + (Kd >> 2) : Kd;

  __shared__ __align__(16) unsigned short As[128 * 64];
  __shared__ __align__(16) unsigned short Bs[128 * 64];

  const int tid = threadIdx.x, w = tid >> 6, l = tid & 63;

  const unsigned short* asrc[4];
  const float* bsrc[4];
#pragma unroll
  for (int i = 0; i < 4; i++) {
    int r = w * 8 + i * 32 + (l >> 3);
    int gr = m0 + r; if (gr > M - 1) gr = M - 1;
    long grow;
    if constexpr (MODE == 0) grow = list[roff + gr];
    else grow = roff + gr;
    asrc[i] = Abase + grow * (long)ldA + (l & 7) * 8;
    bsrc[i] = Bp + (size_t)(n0 + r) * (size_t)Kd + (l & 7) * 8;
  }
  const int ldstB = w * 512 + (l >> 3) * 64 + (((l & 7) ^ (l >> 3)) * 8);

  f32x4 acc[4][4] = {};
  const int wm = w >> 1, wn = w & 1;
  const int fr = l & 15, fk = (l >> 4) * 8;
  const int col0 = (((l >> 4) + 0) ^ (l & 7)) * 8;
  const int col1 = (((l >> 4) + 4) ^ (l & 7)) * 8;

  float4 rb[4][2];
#define LOADB(K0)                                            \
  _Pragma("unroll") for (int i = 0; i < 4; i++) {            \
    rb[i][0] = *(const float4*)(bsrc[i] + (K0));             \
    rb[i][1] = *(const float4*)(bsrc[i] + (K0) + 4);         \
  }

  LOADB(kBeg);

  for (int k0 = kBeg; k0 < kEnd; k0 += 64) {
#pragma unroll
    for (int i = 0; i < 4; i++) {
      __builtin_amdgcn_global_load_lds(
          (const __attribute__((address_space(1))) unsigned int*)(const void*)(asrc[i] + k0),
          (__attribute__((address_space(3))) unsigned int*)(void*)(As + w * 512 + i * 2048),
          16, 0, 0);
      uint4 pb;
      pb.x = cvtpk(rb[i][0].x, rb[i][0].y);
      pb.y = cvtpk(rb[i][0].z, rb[i][0].w);
      pb.z = cvtpk(rb[i][1].x, rb[i][1].y);
      pb.w = cvtpk(rb[i][1].z, rb[i][1].w);
      *(uint4*)(Bs + ldstB + i * 2048) = pb;
    }
    __syncthreads();  // drains A gloads + B writes
    if (k0 + 64 < kEnd) LOADB(k0 + 64);  // B prefetch hides HBM under MFMA
#pragma unroll
    for (int ks = 0; ks < 2; ks++) {
      const int ck = ks ? col1 : col0;
      bf16x8 af[4], bfr[4];
#pragma unroll
      for (int am = 0; am < 4; am++)
        af[am] = *(const bf16x8*)(As + (wm * 64 + am * 16 + fr) * 64 + ks * 32 + fk);
#pragma unroll
      for (int bn = 0; bn < 4; bn++)
        bfr[bn] = *(const bf16x8*)(Bs + (wn * 64 + bn * 16 + fr) * 64 + ck);
#pragma unroll
      for (int am = 0; am < 4; am++)
#pragma unroll
        for (int bn = 0; bn < 4; bn++)
          acc[am][bn] = __builtin_amdgcn_mfma_f32_16x16x32_bf16(af[am], bfr[bn], acc[am][bn], 0, 0, 0);
    }
    __syncthreads();
  }
#undef LOADB

  const int r0 = (l >> 4) * 4, cc = l & 15;
#pragma unroll
  for (int am = 0; am < 4; am++) {
#pragma unroll
    for (int bn = 0; bn < 4; bn++) {
      int gn = n0 + wn * 64 + bn * 16 + cc;
      float bv;
      if constexpr (MODE == 1) bv = (kc == 0) ? be[gn] : 0.f;
      else bv = be[gn];
#pragma unroll
      for (int j = 0; j < 4; j++) {
        int gm = m0 + wm * 64 + am * 16 + r0 + j;
        if (gm >= M) continue;
        float v = acc[am][bn][j] + bv;
        if constexpr (MODE == 0) {
          float g = 0.5f * v * (1.f + erff(v * 0.70710678118654752f));
          Cbf[(size_t)(roff + gm) * (size_t)N + gn] = f2bf(g);
        } else {
          Cout[(size_t)kc * ((size_t)kRp * kH) + (size_t)(roff + gm) * (size_t)N + gn] =
              scal[e] * v;
        }
      }
    }
  }
}

// ---------------- head GEMM: A (h_bf) via global_load_lds, B (head_w f32) cvt-staged
__launch_bounds__(256)
__global__ void hgemm_k(const unsigned short* __restrict__ hbf,
                        const float* __restrict__ Bw,
                        const float* __restrict__ bias,
                        float* __restrict__ Cout) {
  int bx = blockIdx.x, by = blockIdx.y;
  {
    int lin = by * gridDim.x + bx;
    int nwg = gridDim.x * gridDim.y;
    int q = nwg >> 3, r = nwg & 7;
    int xcd = lin & 7, idx = lin >> 3;
    int swzb = (xcd < r ? xcd * (q + 1) : r * (q + 1) + (xcd - r) * q) + idx;
    bx = swzb % gridDim.x;
    by = swzb / gridDim.x;
  }
  const int m0 = bx * 128;
  const int n0 = by * 128;

  __shared__ __align__(16) unsigned short As[128 * 64];
  __shared__ __align__(16) unsigned short Bs[128 * 64];

  const int tid = threadIdx.x, w = tid >> 6, l = tid & 63;

  const unsigned short* asrc[4];
  const float* bsrc[4];
#pragma unroll
  for (int i = 0; i < 4; i++) {
    int r = w * 8 + i * 32 + (l >> 3);
    asrc[i] = hbf + (size_t)(m0 + r) * kH + (l & 7) * 8;
    bsrc[i] = Bw + (size_t)(n0 + r) * kH + (l & 7) * 8;
  }
  const int ldstB = w * 512 + (l >> 3) * 64 + (((l & 7) ^ (l >> 3)) * 8);

  f32x4 acc[4][4] = {};
  const int wm = w >> 1, wn = w & 1;
  const int fr = l & 15, fk = (l >> 4) * 8;
  const int col0 = (((l >> 4) + 0) ^ (l & 7)) * 8;
  const int col1 = (((l >> 4) + 4) ^ (l & 7)) * 8;

  float4 rb[4][2];
#define LOADB(K0)                                            \
  _Pragma("unroll") for (int i = 0; i < 4; i++) {            \
    rb[i][0] = *(const float4*)(bsrc[i] + (K0));             \
    rb[i][1] = *(const float4*)(bsrc[i] + (K0) + 4);         \
  }

  LOADB(0);

  for (int k0 = 0; k0 < kH; k0 += 64) {
#pragma unroll
    for (int i = 0; i < 4; i++) {
      __builtin_amdgcn_global_load_lds(
          (const __attribute__((address_space(1))) unsigned int*)(const void*)(asrc[i] + k0),
          (__attribute__((address_space(3))) unsigned int*)(void*)(As + w * 512 + i * 2048),
          16, 0, 0);
      uint4 pb;
      pb.x = cvtpk(rb[i][0].x, rb[i][0].y);
      pb.y = cvtpk(rb[i][0].z, rb[i][0].w);
      pb.z = cvtpk(rb[i][1].x, rb[i][1].y);
      pb.w = cvtpk(rb[i][1].z, rb[i][1].w);
      *(uint4*)(Bs + ldstB + i * 2048) = pb;
    }
    __syncthreads();
    if (k0 + 64 < kH) LOADB(k0 + 64);
#pragma unroll
    for (int ks = 0; ks < 2; ks++) {
      const int ck = ks ? col1 : col0;
      bf16x8 af[4], bfr[4];
#pragma unroll
      for (int am = 0; am < 4; am++)
        af[am] = *(const bf16x8*)(As + (wm * 64 + am * 16 + fr) * 64 + ks * 32 + fk);
#pragma unroll
      for (int bn = 0; bn < 4; bn++)
        bfr[bn] = *(const bf16x8*)(Bs + (wn * 64 + bn * 16 + fr) * 64 + ck);
#pragma unroll
      for (int am = 0; am < 4; am++)
#pragma unroll
        for (int bn = 0; bn < 4; bn++)
          acc[am][bn] = __builtin_amdgcn_mfma_f32_16x16x32_bf16(af[am], bfr[bn], acc[am][bn], 0, 0, 0);
    }
    __syncthreads();
  }
#undef LOADB

  const int r0 = (l >> 4) * 4, cc = l & 15;
#pragma unroll
  for (int am = 0; am < 4; am++) {
#pragma unroll
    for (int bn = 0; bn < 4; bn++) {
      int gn = n0 + wn * 64 + bn * 16 + cc;
      float bv = bias[gn];
#pragma unroll
      for (int j = 0; j < 4; j++) {
        int gm = m0 + wm * 64 + am * 16 + r0 + j;
        Cout[(size_t)gm * (size_t)kV + gn] = acc[am][bn][j] + bv;
      }
    }
  }
}

// ---------------- launch ----------------

extern "C" void kernel_launch(void* const* d_in, const int* in_sizes, int n_in,
                              void* d_out, int out_size, void* d_ws, size_t ws_size,
                              hipStream_t stream) {
  (void)in_sizes; (void)n_in; (void)out_size; (void)ws_size;
  const int* ids = (const int*)d_in[0];
  const float* emb = (const float*)d_in[1];
  const float* router_w = (const float*)d_in[2];
  const float* router_b = (const float*)d_in[3];
  const float* fc1_w = (const float*)d_in[4];
  const float* fc1_b = (const float*)d_in[5];
  const float* fc2_w = (const float*)d_in[6];
  const float* fc2_b = (const float*)d_in[7];
  const float* ln_g = (const float*)d_in[8];
  const float* ln_b = (const float*)d_in[9];
  const float* head_w = (const float*)d_in[10];
  const float* head_b = (const float*)d_in[11];
  float* out = (float*)d_out;

  // --- workspace layout (~13 MB) ---
  float* ws_f = (float*)d_ws;
  float* h       = ws_f;                          // kT*kH f32
  float* logits  = h + (size_t)kT * kH;           // kT*kE
  float* w_sum   = logits + (size_t)kT * kE;      // kE
  float* scal    = w_sum + kE;                    // kE
  float* aux     = scal + kE;                     // 1
  int* sel  = (int*)(aux + 1);                    // kT*2
  int* cnt  = sel + 2 * kT;                       // kE
  int* off  = cnt + kE;                           // kE
  int* fill = off + kE;                           // kE
  int* list = fill + kE;                          // kRp
  int* pos  = list + kRp;                         // kT*2
  int* blk_e = pos + 2 * kT;                      // kNB
  int* blk_m = blk_e + kNB;                       // kNB
  unsigned short* h_bf = (unsigned short*)(blk_m + kNB);  // kT*kH bf16 (4.2 MB)

  // --- d_out scratch (head overwrites everything at the end) ---
  float* a_f32  = out;                                    // kRp*kI f32
  float* c_comp = a_f32 + (size_t)kRp * kI;               // kSK*kRp*kH f32
  unsigned short* a_bf = (unsigned short*)out;            // kRp*kI bf16

  hipMemsetAsync(aux, 0, sizeof(float), stream);
  gather_k<<<kT, 256, 0, stream>>>(ids, emb, h);

  for (int l = 0; l < kL; l++) {
    hipMemsetAsync(w_sum, 0, kE * sizeof(float), stream);
    hipMemsetAsync(cnt, 0, kE * sizeof(int), stream);
    router_k<<<kT, 256, 0, stream>>>(h, router_w + (size_t)l * kE * kH,
                                     router_b + (size_t)l * kE, logits);
    topk_k<<<kT / 256, 256, 0, stream>>>(logits, sel, w_sum, cnt);
    finalize_k<<<1, 64, 0, stream>>>(cnt, w_sum, scal, off, fill, aux, blk_e, blk_m);
    scatter_k<<<kT / 256, 256, 0, stream>>>(sel, off, fill, list, pos);

    if (l == 0) {
      // layer-1: bf16x2 split MFMA (r14 structure, 2-level decompose)
      tgemm_k<0><<<dim3(kNB, kI / 128), 256, 0, stream>>>(
          h, kH, fc1_w + (size_t)l * kE * kI * kH, fc1_b + (size_t)l * kE * kI,
          a_f32, list, off, cnt, scal, blk_e, blk_m, kI, kH);
      tgemm_k<1><<<dim3(kNB, (kH / 128) * kSK), 256, 0, stream>>>(
          a_f32, kI, fc2_w + (size_t)l * kE * kH * kI, fc2_b + (size_t)l * kE * kH,
          c_comp, list, off, cnt, scal, blk_e, blk_m, kH, kI);
    } else {
      // layer-2: A bf16 gload_lds + B f32 cvt-staged (no weight cvt passes)
      wfgemm_k<0><<<dim3(kNB, kI / 128), 256, 0, stream>>>(
          h_bf, kH, fc1_w + (size_t)l * kE * kI * kH, fc1_b + (size_t)l * kE * kI,
          nullptr, a_bf, list, off, cnt, scal, blk_e, blk_m, kI, kH);
      wfgemm_k<1><<<dim3(kNB, (kH / 128) * kSK), 256, 0, stream>>>(
          a_bf, kI, fc2_w + (size_t)l * kE * kH * kI, fc2_b + (size_t)l * kE * kH,
          c_comp, nullptr, list, off, cnt, scal, blk_e, blk_m, kH, kI);
    }

    combine_ln_k<<<kT, 256, 0, stream>>>(c_comp, pos, h, h_bf,
                                         ln_g + (size_t)l * kH, ln_b + (size_t)l * kH);
  }

  // head: A = h_bf via gload_lds; B = head_w f32 cvt-staged with reg prefetch
  hgemm_k<<<dim3(kT / 128, kV / 128), 256, 0, stream>>>(h_bf, head_w, head_b, out);

  aux_write_k<<<1, 1, 0, stream>>>(out, aux);
}

// Round 18
// 1146.906 us; speedup vs baseline: 1.2376x; 1.0112x over previous
//
#include <hip/hip_runtime.h>
#include <math.h>

// Problem constants
constexpr int kT = 2048;   // tokens (B*S)
constexpr int kH = 1024;   // hidden
constexpr int kI = 4096;   // ffn inner
constexpr int kE = 8;      // experts
constexpr int kV = 32000;  // vocab
constexpr int kL = 2;      // layers
constexpr int kR = 4096;   // total routed rows = K*T
constexpr int kRp = 5120;  // padded compact rows (off[e] 128-aligned)
constexpr int kSK = 4;     // fc2 split-K chunks
constexpr int kNB = kR / 128 + kE - 1;  // 39: max active m-blocks across experts

typedef __attribute__((ext_vector_type(4))) float f32x4;
typedef __attribute__((ext_vector_type(8))) short bf16x8;

// f32 pair -> packed bf16x2 (gfx950 v_cvt_pk_bf16_f32; RNE — same as f2bf)
__device__ inline unsigned cvtpk(float lo, float hi) {
  unsigned r;
  asm("v_cvt_pk_bf16_f32 %0, %1, %2" : "=v"(r) : "v"(lo), "v"(hi));
  return r;
}

__device__ inline unsigned short f2bf(float x) {
  union { float f; unsigned u; } c; c.f = x;
  unsigned u = c.u;
  u += 0x7FFFu + ((u >> 16) & 1u);  // RNE
  return (unsigned short)(u >> 16);
}

// bf16x2 exact-truncation decompose of an f32 pair, packed per level.
// x = x1 + r; x1 = trunc16(x) (exact); x2 = trunc16(r). Dropped cross terms
// (a2b2, a1b3, a3b1) are ~2^-16 relative -> layer-1 rel err ~1.5e-5 (router-safe).
__device__ inline void dec2b(float x, float y, unsigned& p1, unsigned& p2) {
  unsigned ux = __float_as_uint(x), uy = __float_as_uint(y);
  unsigned x1 = ux & 0xFFFF0000u, y1 = uy & 0xFFFF0000u;
  float rx = x - __uint_as_float(x1), ry = y - __uint_as_float(y1);
  p1 = (x1 >> 16) | y1;
  p2 = (__float_as_uint(rx) >> 16) | (__float_as_uint(ry) & 0xFFFF0000u);
}

// LDS swizzle for [128][32]-bf16 tiles (write & read sides; 0 conflicts, r6/r9)
__device__ inline int swz(int e) { return e ^ (((e >> 6) & 3) << 3); }

// ---------------- small per-token kernels ----------------

__global__ void gather_k(const int* __restrict__ ids, const float* __restrict__ emb,
                         float* __restrict__ h) {
  int t = blockIdx.x;
  int id = ids[t];
  const float4* src = (const float4*)(emb + (size_t)id * kH);
  float4* dst = (float4*)(h + (size_t)t * kH);
  dst[threadIdx.x] = src[threadIdx.x];
}

__global__ void router_k(const float* __restrict__ h, const float* __restrict__ rw,
                         const float* __restrict__ rb, float* __restrict__ logits) {
  int t = blockIdx.x;
  int lg = threadIdx.x & 31;
  int e = threadIdx.x >> 5;
  const float* hr = h + (size_t)t * kH;
  const float* wr = rw + (size_t)e * kH;
  float p = 0.f;
  for (int k = lg * 4; k < kH; k += 128) {
    float4 a = *(const float4*)(hr + k);
    float4 b = *(const float4*)(wr + k);
    p += a.x * b.x + a.y * b.y + a.z * b.z + a.w * b.w;
  }
  for (int o = 16; o > 0; o >>= 1) p += __shfl_down(p, o, 32);
  if (lg == 0) logits[t * kE + e] = p + rb[e];
}

__global__ void topk_k(const float* __restrict__ logits, int* __restrict__ sel,
                       float* __restrict__ w_sum, int* __restrict__ cnt) {
  int t = blockIdx.x * blockDim.x + threadIdx.x;
  if (t >= kT) return;
  float v[8];
#pragma unroll
  for (int e = 0; e < 8; e++) v[e] = logits[t * 8 + e];
  int e1 = 0; float v1 = v[0];
#pragma unroll
  for (int e = 1; e < 8; e++) if (v[e] > v1) { v1 = v[e]; e1 = e; }
  int e2 = -1; float v2 = -3.4e38f;
#pragma unroll
  for (int e = 0; e < 8; e++) if (e != e1 && v[e] > v2) { v2 = v[e]; e2 = e; }
  float z = expf(v2 - v1);
  float w1 = 1.f / (1.f + z);
  float w2 = z * w1;
  sel[t * 2] = e1;
  sel[t * 2 + 1] = e2;
  atomicAdd(&w_sum[e1], w1);
  atomicAdd(&w_sum[e2], w2);
  atomicAdd(&cnt[e1], 1);
  atomicAdd(&cnt[e2], 1);
}

// builds 128-ALIGNED expert offsets + block table
__global__ void finalize_k(const int* __restrict__ cnt, const float* __restrict__ w_sum,
                           float* __restrict__ scal, int* __restrict__ off,
                           int* __restrict__ fill, float* __restrict__ aux,
                           int* __restrict__ blk_e, int* __restrict__ blk_m) {
  if (threadIdx.x == 0) {
    int o = 0;
    float a = 0.f;
    for (int e = 0; e < 8; e++) {
      off[e] = o;
      o += (cnt[e] + 127) & ~127;   // 128-aligned padding
      fill[e] = 0;
      int c = cnt[e];
      scal[e] = c > 0 ? w_sum[e] / (float)c : 0.f;
      float d = (float)c - 256.f;
      a += d * d;
    }
    aux[0] += 0.01f * (a * 0.125f);
    int nb = 0;
    for (int e = 0; e < 8; e++)
      for (int m = 0; m < cnt[e]; m += 128) { blk_e[nb] = e; blk_m[nb] = m; nb++; }
    for (int i = nb; i < kNB; i++) { blk_e[i] = -1; blk_m[i] = 0; }
  }
}

// records each token's compact-slot position for the combine step
__global__ void scatter_k(const int* __restrict__ sel, const int* __restrict__ off,
                          int* __restrict__ fill, int* __restrict__ list,
                          int* __restrict__ pos) {
  int t = blockIdx.x * blockDim.x + threadIdx.x;
  if (t >= kT) return;
#pragma unroll
  for (int s = 0; s < 2; s++) {
    int e = sel[t * 2 + s];
    int p = atomicAdd(&fill[e], 1);
    int slot = off[e] + p;
    list[slot] = t;
    pos[t * 2 + s] = slot;
  }
}

// out[t] = LayerNorm( sum_{s in 2} sum_{kc in 4} c_comp[kc][pos[t,s]] ) -> h (f32)
// AND h_bf (bf16, RNE) -- fused cvt
__global__ void combine_ln_k(const float* __restrict__ ccomp, const int* __restrict__ pos,
                             float* __restrict__ h, unsigned short* __restrict__ hbf,
                             const float* __restrict__ g, const float* __restrict__ b) {
  int t = blockIdx.x;
  int s0 = pos[t * 2], s1 = pos[t * 2 + 1];
  int k = threadIdx.x * 4;
  float4 v = {0.f, 0.f, 0.f, 0.f};
#pragma unroll
  for (int kc = 0; kc < kSK; kc++) {
    const float* base = ccomp + (size_t)kc * ((size_t)kRp * kH);
    float4 a = *(const float4*)(base + (size_t)s0 * kH + k);
    float4 c = *(const float4*)(base + (size_t)s1 * kH + k);
    v.x += a.x + c.x; v.y += a.y + c.y; v.z += a.z + c.z; v.w += a.w + c.w;
  }
  float s = v.x + v.y + v.z + v.w;
  float sq = v.x * v.x + v.y * v.y + v.z * v.z + v.w * v.w;
  for (int o = 32; o > 0; o >>= 1) {
    s += __shfl_down(s, o);
    sq += __shfl_down(sq, o);
  }
  __shared__ float ss[4], sqs[4];
  int wave = threadIdx.x >> 6, lane = threadIdx.x & 63;
  if (lane == 0) { ss[wave] = s; sqs[wave] = sq; }
  __syncthreads();
  __shared__ float mu, inv;
  if (threadIdx.x == 0) {
    float st = ss[0] + ss[1] + ss[2] + ss[3];
    float sqt = sqs[0] + sqs[1] + sqs[2] + sqs[3];
    float m = st / (float)kH;
    float var = sqt / (float)kH - m * m;
    mu = m;
    inv = 1.f / sqrtf(var + 1e-5f);
  }
  __syncthreads();
  float4 gg = *(const float4*)(g + k);
  float4 bb = *(const float4*)(b + k);
  float4 o;
  o.x = (v.x - mu) * inv * gg.x + bb.x;
  o.y = (v.y - mu) * inv * gg.y + bb.y;
  o.z = (v.z - mu) * inv * gg.z + bb.z;
  o.w = (v.w - mu) * inv * gg.w + bb.w;
  *(float4*)(h + (size_t)t * kH + k) = o;
  uint2 pk;
  pk.x = (unsigned)f2bf(o.x) | ((unsigned)f2bf(o.y) << 16);
  pk.y = (unsigned)f2bf(o.z) | ((unsigned)f2bf(o.w) << 16);
  *(uint2*)(hbf + (size_t)t * kH + k) = pk;
}

__global__ void aux_write_k(float* __restrict__ out, const float* __restrict__ aux) {
  out[(size_t)kT * kV] = aux[0];
}

// ---------------- bf16x2 split-precision MFMA GEMM (layer-1 FFN) ----------------
// r14 structure (256 thr, 4 waves, 2-barrier, swizzled LDS, 0 conflicts) with the
// bf16 split reduced 3->2 levels: 3 MFMA terms/frag (a2b1, a1b2, a1b1), 2 LDS
// planes (32 KB), dec and LDS traffic cut ~1/3-1/2. Rel err ~1.5e-5 (router-safe).
// MODE 0: fc1 (A rows via token list, GELU -> f32 a_buf)
// MODE 1: fc2 (A = compact rows, split-K=4, scal*(acc[+bias]) -> per-chunk compact)
template <int MODE>
__launch_bounds__(256)
__global__ void tgemm_k(const float* __restrict__ Abase, int ldA,
                        const float* __restrict__ Bbase,
                        const float* __restrict__ bias,
                        float* __restrict__ Cout,
                        const int* __restrict__ list,
                        const int* __restrict__ off,
                        const int* __restrict__ cnt,
                        const float* __restrict__ scal,
                        const int* __restrict__ blk_e,
                        const int* __restrict__ blk_m,
                        int N, int Kd) {
  const int e = blk_e[blockIdx.x];
  if (e < 0) return;
  const int m0 = blk_m[blockIdx.x];
  const int M = cnt[e];
  int nb = blockIdx.y, kc = 0;
  if constexpr (MODE == 1) { nb = blockIdx.y >> 2; kc = blockIdx.y & 3; }
  const int n0 = nb * 128;
  const int roff = off[e];
  const float* Bp = Bbase + (size_t)e * (size_t)N * (size_t)Kd;
  const float* be = bias + (size_t)e * (size_t)N;
  const int kBeg = (MODE == 1) ? kc * (Kd >> 2) : 0;
  const int kEnd = (MODE == 1) ? kBeg + (Kd >> 2) : Kd;

  __shared__ __align__(16) unsigned short As[2][128 * 32];
  __shared__ __align__(16) unsigned short Bs[2][128 * 32];

  const int tid = threadIdx.x, w = tid >> 6, l = tid & 63;

  // staging: thread covers tile-row tid>>1, col-half (tid&1)*16
  const int srow = tid >> 1, scolh = (tid & 1) * 16;
  int gr = m0 + srow; if (gr > M - 1) gr = M - 1;
  long arow;
  if constexpr (MODE == 0) arow = list[roff + gr];
  else arow = roff + gr;
  const float* asrc = Abase + arow * (long)ldA + scolh;
  const float* bsrc = Bp + (size_t)(n0 + srow) * (size_t)Kd + scolh;
  const int e0 = srow * 32 + scolh;
  const int s0 = swz(e0), s1 = swz(e0 + 8);

  f32x4 acc[4][4] = {};
  const int wm = w >> 1, wn = w & 1;
  const int fr = l & 15, fk = (l >> 4) * 8;

  float4 rva[4], rvb[4];
  unsigned qa1[8], qa2[8], qb1[8], qb2[8];

#define LOADT(K0)                                   \
  _Pragma("unroll") for (int i = 0; i < 4; i++) {   \
    rva[i] = *(const float4*)(asrc + (K0) + i * 4); \
    rvb[i] = *(const float4*)(bsrc + (K0) + i * 4); \
  }

#define DECALL()                                               \
  {                                                            \
    float xa[16], xb[16];                                      \
    *(float4*)&xa[0] = rva[0]; *(float4*)&xa[4] = rva[1];      \
    *(float4*)&xa[8] = rva[2]; *(float4*)&xa[12] = rva[3];     \
    *(float4*)&xb[0] = rvb[0]; *(float4*)&xb[4] = rvb[1];      \
    *(float4*)&xb[8] = rvb[2]; *(float4*)&xb[12] = rvb[3];     \
    _Pragma("unroll") for (int i = 0; i < 8; i++) {            \
      dec2b(xa[2 * i], xa[2 * i + 1], qa1[i], qa2[i]);         \
      dec2b(xb[2 * i], xb[2 * i + 1], qb1[i], qb2[i]);         \
    }                                                          \
  }

  LOADT(kBeg);
  DECALL();

  for (int k0 = kBeg; k0 < kEnd; k0 += 32) {
    // serial segment: just the 8 LDS writes of the pre-decomposed tile
    *(uint4*)&As[0][s0] = *(uint4*)&qa1[0]; *(uint4*)&As[0][s1] = *(uint4*)&qa1[4];
    *(uint4*)&As[1][s0] = *(uint4*)&qa2[0]; *(uint4*)&As[1][s1] = *(uint4*)&qa2[4];
    *(uint4*)&Bs[0][s0] = *(uint4*)&qb1[0]; *(uint4*)&Bs[0][s1] = *(uint4*)&qb1[4];
    *(uint4*)&Bs[1][s0] = *(uint4*)&qb2[0]; *(uint4*)&Bs[1][s1] = *(uint4*)&qb2[4];
    __syncthreads();
    const bool more = (k0 + 32 < kEnd);
    if (more) LOADT(k0 + 32);  // global issue; returns under MFMA phase

    bf16x8 bf1[4], bf2[4];
#pragma unroll
    for (int bn = 0; bn < 4; bn++) {
      int se = swz((wn * 64 + bn * 16 + fr) * 32 + fk);
      bf1[bn] = *(const bf16x8*)(&Bs[0][se]);
      bf2[bn] = *(const bf16x8*)(&Bs[1][se]);
    }
#pragma unroll
    for (int am = 0; am < 4; am++) {
      int se = swz((wm * 64 + am * 16 + fr) * 32 + fk);
      bf16x8 a1 = *(const bf16x8*)(&As[0][se]);
      bf16x8 a2 = *(const bf16x8*)(&As[1][se]);
#pragma unroll
      for (int bn = 0; bn < 4; bn++) {
        f32x4 c = acc[am][bn];
        c = __builtin_amdgcn_mfma_f32_16x16x32_bf16(a2, bf1[bn], c, 0, 0, 0);
        c = __builtin_amdgcn_mfma_f32_16x16x32_bf16(a1, bf2[bn], c, 0, 0, 0);
        c = __builtin_amdgcn_mfma_f32_16x16x32_bf16(a1, bf1[bn], c, 0, 0, 0);
        acc[am][bn] = c;
      }
    }
    if (more) DECALL();  // VALU stream; compiler interleaves with MFMA above
    __syncthreads();
  }
#undef LOADT
#undef DECALL

  // C/D layout: col = lane&15, row = (lane>>4)*4 + j  (m89/m91-verified)
  const int r0 = (l >> 4) * 4, cc = l & 15;
#pragma unroll
  for (int am = 0; am < 4; am++) {
#pragma unroll
    for (int bn = 0; bn < 4; bn++) {
      int gn = n0 + wn * 64 + bn * 16 + cc;
      float bv;
      if constexpr (MODE == 1) bv = (kc == 0) ? be[gn] : 0.f;
      else bv = be[gn];
#pragma unroll
      for (int j = 0; j < 4; j++) {
        int gm = m0 + wm * 64 + am * 16 + r0 + j;
        if (gm >= M) continue;
        float v = acc[am][bn][j] + bv;
        if constexpr (MODE == 0) {
          float g = 0.5f * v * (1.f + erff(v * 0.70710678118654752f));
          Cout[(size_t)(roff + gm) * (size_t)N + gn] = g;
        } else {
          Cout[(size_t)kc * ((size_t)kRp * kH) + (size_t)(roff + gm) * (size_t)N + gn] =
              scal[e] * v;
        }
      }
    }
  }
}

// ---------------- layer-2 GEMM: A (bf16) via global_load_lds, B (f32) cvt-staged ----
// MODE 0: fc1-l2 (A = h_bf rows via list gather; GELU -> bf16 a_bf)
// MODE 1: fc2-l2 (A = a_bf compact rows; split-K=4; scal*(acc[+bias]) -> c_comp f32)
template <int MODE>
__launch_bounds__(256)
__global__ void wfgemm_k(const unsigned short* __restrict__ Abase, int ldA,
                         const float* __restrict__ Bbase,
                         const float* __restrict__ bias,
                         float* __restrict__ Cout,
                         unsigned short* __restrict__ Cbf,
                         const int* __restrict__ list,
                         const int* __restrict__ off,
                         const int* __restrict__ cnt,
                         const float* __restrict__ scal,
                         const int* __restrict__ blk_e,
                         const int* __restrict__ blk_m,
                         int N, int Kd) {
  const int e = blk_e[blockIdx.x];
  if (e < 0) return;
  const int m0 = blk_m[blockIdx.x];
  const int M = cnt[e];
  int nb = blockIdx.y, kc = 0;
  if constexpr (MODE == 1) { nb = blockIdx.y >> 2; kc = blockIdx.y & 3; }
  const int n0 = nb * 128;
  const int roff = off[e];
  const float* Bp = Bbase + (size_t)e * (size_t)N * (size_t)Kd;
  const float* be = bias + (size_t)e * (size_t)N;
  const int kBeg = (MODE == 1) ? kc * (Kd >> 2) : 0;
  const int kEnd = (MODE == 1) ? kBeg + (Kd >> 2) : Kd;

  __shared__ __align__(16) unsigned short As[128 * 64];
  __shared__ __align__(16) unsigned short Bs[128 * 64];

  const int tid = threadIdx.x, w = tid >> 6, l = tid & 63;

  const unsigned short* asrc[4];
  const float* bsrc[4];
#pragma unroll
  for (int i = 0; i < 4; i++) {
    int r = w * 8 + i * 32 + (l >> 3);
    int gr = m0 + r; if (gr > M - 1) gr = M - 1;
    long grow;
    if constexpr (MODE == 0) grow = list[roff + gr];
    else grow = roff + gr;
    asrc[i] = Abase + grow * (long)ldA + (l & 7) * 8;
    bsrc[i] = Bp + (size_t)(n0 + r) * (size_t)Kd + (l & 7) * 8;
  }
  const int ldstB = w * 512 + (l >> 3) * 64 + (((l & 7) ^ (l >> 3)) * 8);

  f32x4 acc[4][4] = {};
  const int wm = w >> 1, wn = w & 1;
  const int fr = l & 15, fk = (l >> 4) * 8;
  const int col0 = (((l >> 4) + 0) ^ (l & 7)) * 8;
  const int col1 = (((l >> 4) + 4) ^ (l & 7)) * 8;

  float4 rb[4][2];
#define LOADB(K0)                                            \
  _Pragma("unroll") for (int i = 0; i < 4; i++) {            \
    rb[i][0] = *(const float4*)(bsrc[i] + (K0));             \
    rb[i][1] = *(const float4*)(bsrc[i] + (K0) + 4);         \
  }

  LOADB(kBeg);

  for (int k0 = kBeg; k0 < kEnd; k0 += 64) {
#pragma unroll
    for (int i = 0; i < 4; i++) {
      __builtin_amdgcn_global_load_lds(
          (const __attribute__((address_space(1))) unsigned int*)(const void*)(asrc[i] + k0),
          (__attribute__((address_space(3))) unsigned int*)(void*)(As + w * 512 + i * 2048),
          16, 0, 0);
      uint4 pb;
      pb.x = cvtpk(rb[i][0].x, rb[i][0].y);
      pb.y = cvtpk(rb[i][0].z, rb[i][0].w);
      pb.z = cvtpk(rb[i][1].x, rb[i][1].y);
      pb.w = cvtpk(rb[i][1].z, rb[i][1].w);
      *(uint4*)(Bs + ldstB + i * 2048) = pb;
    }
    __syncthreads();  // drains A gloads + B writes
    if (k0 + 64 < kEnd) LOADB(k0 + 64);  // B prefetch hides HBM under MFMA
#pragma unroll
    for (int ks = 0; ks < 2; ks++) {
      const int ck = ks ? col1 : col0;
      bf16x8 af[4], bfr[4];
#pragma unroll
      for (int am = 0; am < 4; am++)
        af[am] = *(const bf16x8*)(As + (wm * 64 + am * 16 + fr) * 64 + ks * 32 + fk);
#pragma unroll
      for (int bn = 0; bn < 4; bn++)
        bfr[bn] = *(const bf16x8*)(Bs + (wn * 64 + bn * 16 + fr) * 64 + ck);
#pragma unroll
      for (int am = 0; am < 4; am++)
#pragma unroll
        for (int bn = 0; bn < 4; bn++)
          acc[am][bn] = __builtin_amdgcn_mfma_f32_16x16x32_bf16(af[am], bfr[bn], acc[am][bn], 0, 0, 0);
    }
    __syncthreads();
  }
#undef LOADB

  const int r0 = (l >> 4) * 4, cc = l & 15;
#pragma unroll
  for (int am = 0; am < 4; am++) {
#pragma unroll
    for (int bn = 0; bn < 4; bn++) {
      int gn = n0 + wn * 64 + bn * 16 + cc;
      float bv;
      if constexpr (MODE == 1) bv = (kc == 0) ? be[gn] : 0.f;
      else bv = be[gn];
#pragma unroll
      for (int j = 0; j < 4; j++) {
        int gm = m0 + wm * 64 + am * 16 + r0 + j;
        if (gm >= M) continue;
        float v = acc[am][bn][j] + bv;
        if constexpr (MODE == 0) {
          float g = 0.5f * v * (1.f + erff(v * 0.70710678118654752f));
          Cbf[(size_t)(roff + gm) * (size_t)N + gn] = f2bf(g);
        } else {
          Cout[(size_t)kc * ((size_t)kRp * kH) + (size_t)(roff + gm) * (size_t)N + gn] =
              scal[e] * v;
        }
      }
    }
  }
}

// ---------------- head GEMM: A (h_bf) via global_load_lds, B (head_w f32) cvt-staged
__launch_bounds__(256)
__global__ void hgemm_k(const unsigned short* __restrict__ hbf,
                        const float* __restrict__ Bw,
                        const float* __restrict__ bias,
                        float* __restrict__ Cout) {
  int bx = blockIdx.x, by = blockIdx.y;
  {
    int lin = by * gridDim.x + bx;
    int nwg = gridDim.x * gridDim.y;
    int q = nwg >> 3, r = nwg & 7;
    int xcd = lin & 7, idx = lin >> 3;
    int swzb = (xcd < r ? xcd * (q + 1) : r * (q + 1) + (xcd - r) * q) + idx;
    bx = swzb % gridDim.x;
    by = swzb / gridDim.x;
  }
  const int m0 = bx * 128;
  const int n0 = by * 128;

  __shared__ __align__(16) unsigned short As[128 * 64];
  __shared__ __align__(16) unsigned short Bs[128 * 64];

  const int tid = threadIdx.x, w = tid >> 6, l = tid & 63;

  const unsigned short* asrc[4];
  const float* bsrc[4];
#pragma unroll
  for (int i = 0; i < 4; i++) {
    int r = w * 8 + i * 32 + (l >> 3);
    asrc[i] = hbf + (size_t)(m0 + r) * kH + (l & 7) * 8;
    bsrc[i] = Bw + (size_t)(n0 + r) * kH + (l & 7) * 8;
  }
  const int ldstB = w * 512 + (l >> 3) * 64 + (((l & 7) ^ (l >> 3)) * 8);

  f32x4 acc[4][4] = {};
  const int wm = w >> 1, wn = w & 1;
  const int fr = l & 15, fk = (l >> 4) * 8;
  const int col0 = (((l >> 4) + 0) ^ (l & 7)) * 8;
  const int col1 = (((l >> 4) + 4) ^ (l & 7)) * 8;

  float4 rb[4][2];
#define LOADB(K0)                                            \
  _Pragma("unroll") for (int i = 0; i < 4; i++) {            \
    rb[i][0] = *(const float4*)(bsrc[i] + (K0));             \
    rb[i][1] = *(const float4*)(bsrc[i] + (K0) + 4);         \
  }

  LOADB(0);

  for (int k0 = 0; k0 < kH; k0 += 64) {
#pragma unroll
    for (int i = 0; i < 4; i++) {
      __builtin_amdgcn_global_load_lds(
          (const __attribute__((address_space(1))) unsigned int*)(const void*)(asrc[i] + k0),
          (__attribute__((address_space(3))) unsigned int*)(void*)(As + w * 512 + i * 2048),
          16, 0, 0);
      uint4 pb;
      pb.x = cvtpk(rb[i][0].x, rb[i][0].y);
      pb.y = cvtpk(rb[i][0].z, rb[i][0].w);
      pb.z = cvtpk(rb[i][1].x, rb[i][1].y);
      pb.w = cvtpk(rb[i][1].z, rb[i][1].w);
      *(uint4*)(Bs + ldstB + i * 2048) = pb;
    }
    __syncthreads();
    if (k0 + 64 < kH) LOADB(k0 + 64);
#pragma unroll
    for (int ks = 0; ks < 2; ks++) {
      const int ck = ks ? col1 : col0;
      bf16x8 af[4], bfr[4];
#pragma unroll
      for (int am = 0; am < 4; am++)
        af[am] = *(const bf16x8*)(As + (wm * 64 + am * 16 + fr) * 64 + ks * 32 + fk);
#pragma unroll
      for (int bn = 0; bn < 4; bn++)
        bfr[bn] = *(const bf16x8*)(Bs + (wn * 64 + bn * 16 + fr) * 64 + ck);
#pragma unroll
      for (int am = 0; am < 4; am++)
#pragma unroll
        for (int bn = 0; bn < 4; bn++)
          acc[am][bn] = __builtin_amdgcn_mfma_f32_16x16x32_bf16(af[am], bfr[bn], acc[am][bn], 0, 0, 0);
    }
    __syncthreads();
  }
#undef LOADB

  const int r0 = (l >> 4) * 4, cc = l & 15;
#pragma unroll
  for (int am = 0; am < 4; am++) {
#pragma unroll
    for (int bn = 0; bn < 4; bn++) {
      int gn = n0 + wn * 64 + bn * 16 + cc;
      float bv = bias[gn];
#pragma unroll
      for (int j = 0; j < 4; j++) {
        int gm = m0 + wm * 64 + am * 16 + r0 + j;
        Cout[(size_t)gm * (size_t)kV + gn] = acc[am][bn][j] + bv;
      }
    }
  }
}

// ---------------- launch ----------------

extern "C" void kernel_launch(void* const* d_in, const int* in_sizes, int n_in,
                              void* d_out, int out_size, void* d_ws, size_t ws_size,
                              hipStream_t stream) {
  (void)in_sizes; (void)n_in; (void)out_size; (void)ws_size;
  const int* ids = (const int*)d_in[0];
  const float* emb = (const float*)d_in[1];
  const float* router_w = (const float*)d_in[2];
  const float* router_b = (const float*)d_in[3];
  const float* fc1_w = (const float*)d_in[4];
  const float* fc1_b = (const float*)d_in[5];
  const float* fc2_w = (const float*)d_in[6];
  const float* fc2_b = (const float*)d_in[7];
  const float* ln_g = (const float*)d_in[8];
  const float* ln_b = (const float*)d_in[9];
  const float* head_w = (const float*)d_in[10];
  const float* head_b = (const float*)d_in[11];
  float* out = (float*)d_out;

  // --- workspace layout (~13 MB) ---
  float* ws_f = (float*)d_ws;
  float* h       = ws_f;                          // kT*kH f32
  float* logits  = h + (size_t)kT * kH;           // kT*kE
  float* w_sum   = logits + (size_t)kT * kE;      // kE
  float* scal    = w_sum + kE;                    // kE
  float* aux     = scal + kE;                     // 1
  int* sel  = (int*)(aux + 1);                    // kT*2
  int* cnt  = sel + 2 * kT;                       // kE
  int* off  = cnt + kE;                           // kE
  int* fill = off + kE;                           // kE
  int* list = fill + kE;                          // kRp
  int* pos  = list + kRp;                         // kT*2
  int* blk_e = pos + 2 * kT;                      // kNB
  int* blk_m = blk_e + kNB;                       // kNB
  unsigned short* h_bf = (unsigned short*)(blk_m + kNB);  // kT*kH bf16 (4.2 MB)

  // --- d_out scratch (head overwrites everything at the end) ---
  float* a_f32  = out;                                    // kRp*kI f32
  float* c_comp = a_f32 + (size_t)kRp * kI;               // kSK*kRp*kH f32
  unsigned short* a_bf = (unsigned short*)out;            // kRp*kI bf16

  hipMemsetAsync(aux, 0, sizeof(float), stream);
  gather_k<<<kT, 256, 0, stream>>>(ids, emb, h);

  for (int l = 0; l < kL; l++) {
    hipMemsetAsync(w_sum, 0, kE * sizeof(float), stream);
    hipMemsetAsync(cnt, 0, kE * sizeof(int), stream);
    router_k<<<kT, 256, 0, stream>>>(h, router_w + (size_t)l * kE * kH,
                                     router_b + (size_t)l * kE, logits);
    topk_k<<<kT / 256, 256, 0, stream>>>(logits, sel, w_sum, cnt);
    finalize_k<<<1, 64, 0, stream>>>(cnt, w_sum, scal, off, fill, aux, blk_e, blk_m);
    scatter_k<<<kT / 256, 256, 0, stream>>>(sel, off, fill, list, pos);

    if (l == 0) {
      // layer-1: bf16x2 split MFMA (r14 structure, 2-level decompose)
      tgemm_k<0><<<dim3(kNB, kI / 128), 256, 0, stream>>>(
          h, kH, fc1_w + (size_t)l * kE * kI * kH, fc1_b + (size_t)l * kE * kI,
          a_f32, list, off, cnt, scal, blk_e, blk_m, kI, kH);
      tgemm_k<1><<<dim3(kNB, (kH / 128) * kSK), 256, 0, stream>>>(
          a_f32, kI, fc2_w + (size_t)l * kE * kH * kI, fc2_b + (size_t)l * kE * kH,
          c_comp, list, off, cnt, scal, blk_e, blk_m, kH, kI);
    } else {
      // layer-2: A bf16 gload_lds + B f32 cvt-staged (no weight cvt passes)
      wfgemm_k<0><<<dim3(kNB, kI / 128), 256, 0, stream>>>(
          h_bf, kH, fc1_w + (size_t)l * kE * kI * kH, fc1_b + (size_t)l * kE * kI,
          nullptr, a_bf, list, off, cnt, scal, blk_e, blk_m, kI, kH);
      wfgemm_k<1><<<dim3(kNB, (kH / 128) * kSK), 256, 0, stream>>>(
          a_bf, kI, fc2_w + (size_t)l * kE * kH * kI, fc2_b + (size_t)l * kE * kH,
          c_comp, nullptr, list, off, cnt, scal, blk_e, blk_m, kH, kI);
    }

    combine_ln_k<<<kT, 256, 0, stream>>>(c_comp, pos, h, h_bf,
                                         ln_g + (size_t)l * kH, ln_b + (size_t)l * kH);
  }

  // head: A = h_bf via gload_lds; B = head_w f32 cvt-staged with reg prefetch
  hgemm_k<<<dim3(kT / 128, kV / 128), 256, 0, stream>>>(h_bf, head_w, head_b, out);

  aux_write_k<<<1, 1, 0, stream>>>(out, aux);
}